// Round 10
// baseline (640.039 us; speedup 1.0000x reference)
//
#include <hip/hip_runtime.h>

// ============================================================================
// Elman tanh-SSM: x_t = tanh(x_{t-1}A^T + u_t B^T); y_t = x_t C^T + u_t D^T
// T=4096, N=32, F=512, f32 in/out.
//
//  K0: convert A,B,C,D -> bf16
//  K1: ubT = (u @ B^T) transposed [t][i][n]
//  K2: chunked-parallel scan -> x_hist bf16 (unchanged from round 5)
//  K3: y = x_hist @ C^T + u @ D^T
//
// GEMM schedule (T3/T4): 256x128 tile, BK=32, 256 thr (4 waves 2x2,
// per-wave 128x64 acc[8][4] -> 43.7 FLOP/LDS-byte), dbuf 48KB LDS,
// launch_bounds(256,2) -> 2 WGs/CU. Two RAW barriers per K-step with
// COUNTED vmcnt (next-tile loads stay in flight across the barrier):
// bar1 = vmcnt(N)+lgkm(0)+s_barrier (stage(k) complete+visible);
// bar2 = raw s_barrier (reads done before buf re-staged). f32-u operand:
// issue-early/write-late (T14), single pf.
// Round-10 fix: in-loop stageA/stageB calls were missing w,l args.
// ============================================================================

typedef unsigned int u32;
typedef __attribute__((ext_vector_type(8))) short short8;
typedef __attribute__((ext_vector_type(4))) short short4v;
typedef __attribute__((ext_vector_type(4))) float f32x4;

#define AS1 __attribute__((address_space(1)))
#define AS3 __attribute__((address_space(3)))

static constexpr int TT     = 4096;
static constexpr int NBATCH = 32;
static constexpr int FD     = 512;
static constexpr int M_TOT  = TT * NBATCH;   // 131072
static constexpr int CHUNK  = 32;
static constexpr int WARM   = 32;
static constexpr int NCHUNK = TT / CHUNK;    // 128
static constexpr int NGRP   = NCHUNK * 2;    // 256 (x2 batch halves)
static constexpr int KREG   = 384;           // serial_k: K-range in registers
static constexpr int TN     = FD * NBATCH;   // 16384 (ubT t-stride)
static constexpr int NWGG   = (M_TOT / 256) * (FD / 128);  // 2048

static constexpr int XROW = 1040;            // serial xbuf row stride bytes
static constexpr int AROW = 272;             // serial Alds row stride bytes
static constexpr int TROW = 528;             // ub transpose row stride bytes
static constexpr int GBUF = 24576;           // GEMM LDS buffer: A 16KB + B 8KB

// raw barrier: LDS visibility only (serial_k)
#define BAR() asm volatile("s_waitcnt lgkmcnt(0)\n\ts_barrier" ::: "memory")

// ---------------- helpers ----------------
__device__ __forceinline__ unsigned short f2bf(float f) {
  u32 u = __builtin_bit_cast(u32, f);
  u32 r = u + 0x7FFFu + ((u >> 16) & 1u);   // RTNE
  return (unsigned short)(r >> 16);
}
__device__ __forceinline__ unsigned short f2bf_fast(float f) {  // half-up
  u32 u = __builtin_bit_cast(u32, f);
  return (unsigned short)((u + 0x8000u) >> 16);
}
__device__ __forceinline__ float bf2f(unsigned short h) {
  u32 u = ((u32)h) << 16;
  return __builtin_bit_cast(float, u);
}
__device__ __forceinline__ u32 pack_bf2(float a, float b) {  // cvt_pk
  __bf16 x = (__bf16)a, y = (__bf16)b;
  return (u32)__builtin_bit_cast(unsigned short, x) |
         ((u32)__builtin_bit_cast(unsigned short, y) << 16);
}

typedef __attribute__((ext_vector_type(8))) __bf16 bf16x8;
__device__ __forceinline__ f32x4 mfma16(short8 a, short8 b, f32x4 c) {
  return __builtin_amdgcn_mfma_f32_16x16x32_bf16(
      __builtin_bit_cast(bf16x8, a), __builtin_bit_cast(bf16x8, b), c, 0, 0, 0);
}

// ---------------- K0: convert A,B,C,D to bf16 ----------------
__global__ void cvt_k(const float* __restrict__ A, const float* __restrict__ B,
                      const float* __restrict__ C, const float* __restrict__ D,
                      unsigned short* __restrict__ Ab, unsigned short* __restrict__ Bb,
                      unsigned short* __restrict__ Cb, unsigned short* __restrict__ Db) {
  const float* s;
  unsigned short* d;
  switch (blockIdx.y) {
    case 0: s = A; d = Ab; break;
    case 1: s = B; d = Bb; break;
    case 2: s = C; d = Cb; break;
    default: s = D; d = Db; break;
  }
  int i = (blockIdx.x * blockDim.x + threadIdx.x) * 4;
  float4 f = *(const float4*)(s + i);
  short4v v;
  v[0] = (short)f2bf(f.x); v[1] = (short)f2bf(f.y);
  v[2] = (short)f2bf(f.z); v[3] = (short)f2bf(f.w);
  *(short4v*)(d + i) = v;
}

// ---------------- 256x128 BK=32 GEMM building blocks (256 threads) ---------
// LDS buffer (24KB): A [256 rows][32k] 64B rows @ +0; B [128][32k] @ +16384.

__device__ __forceinline__ void stageA(const unsigned short* __restrict__ src,
                                       int row0, int k0, char* buf, int w, int l) {
  #pragma unroll
  for (int j = 0; j < 4; ++j) {
    const int q = w * 4 + j;  // 16 issues x 1KB = 16KB
    const unsigned short* gp =
        src + (size_t)(row0 + q * 16 + (l >> 2)) * FD + k0 + (l & 3) * 8;
    __builtin_amdgcn_global_load_lds((const AS1 u32*)gp,
                                     (AS3 u32*)(buf + q * 1024), 16, 0, 0);
  }
}
__device__ __forceinline__ void stageB(const unsigned short* __restrict__ src,
                                       int row0, int k0, char* buf, int w, int l) {
  #pragma unroll
  for (int j = 0; j < 2; ++j) {
    const int q = w * 2 + j;  // 8 issues x 1KB = 8KB
    const unsigned short* gp =
        src + (size_t)(row0 + q * 16 + (l >> 2)) * FD + k0 + (l & 3) * 8;
    __builtin_amdgcn_global_load_lds((const AS1 u32*)gp,
                                     (AS3 u32*)(buf + 16384 + q * 1024), 16, 0, 0);
  }
}

// f32 A-operand: 8 float4/thread (issue) -> bf16-pack ds_write (write)
__device__ __forceinline__ void f32_issue(const float* __restrict__ src, int m0,
                                          int k0, int tid, float4 (&pf)[8]) {
  const int rsub = tid >> 3, c = tid & 7;
  #pragma unroll
  for (int q = 0; q < 8; ++q)
    pf[q] = *(const float4*)(src + (size_t)(m0 + q * 32 + rsub) * FD + k0 + c * 4);
}
__device__ __forceinline__ void f32_write(char* buf, int tid, float4 (&pf)[8]) {
  const int rsub = tid >> 3, c = tid & 7;
  #pragma unroll
  for (int q = 0; q < 8; ++q) {
    uint2 v;
    v.x = pack_bf2(pf[q].x, pf[q].y);
    v.y = pack_bf2(pf[q].z, pf[q].w);
    *(uint2*)(buf + (q * 32 + rsub) * 64 + c * 8) = v;
  }
}

__device__ __forceinline__ void compute32(const char* buf, f32x4 (&acc)[8][4],
                                          int wr, int wc, int lr, int g) {
  short8 af[8], bf[4];
  #pragma unroll
  for (int mi = 0; mi < 8; ++mi)
    af[mi] = *(const short8*)(buf + (wr * 128 + mi * 16 + lr) * 64 + g * 16);
  #pragma unroll
  for (int ni = 0; ni < 4; ++ni)
    bf[ni] = *(const short8*)(buf + 16384 + (wc * 64 + ni * 16 + lr) * 64 + g * 16);
  __builtin_amdgcn_s_setprio(1);
  #pragma unroll
  for (int mi = 0; mi < 8; ++mi)
    #pragma unroll
    for (int ni = 0; ni < 4; ++ni)
      acc[mi][ni] = mfma16(af[mi], bf[ni], acc[mi][ni]);
  __builtin_amdgcn_s_setprio(0);
}

__device__ __forceinline__ void swzgrid(int bid, int& m0, int& i0) {
  int wg = (bid & 7) * (NWGG >> 3) + (bid >> 3);  // XCD-contiguous, bijective
  m0 = (wg >> 2) * 256;                           // n-fastest: 4 i-blocks of an
  i0 = (wg & 3) * 128;                            // m-panel share one L2
}

#define BAR1(N) do { \
    asm volatile("s_waitcnt vmcnt(" #N ") lgkmcnt(0)\n\ts_barrier" ::: "memory"); \
    __builtin_amdgcn_sched_barrier(0); } while (0)
#define BAR2() do { __builtin_amdgcn_sched_barrier(0); \
    asm volatile("s_barrier" ::: "memory"); } while (0)

// ---------------- K1: ubT[t][i][n] = (u @ B^T) -> bf16 transposed ----------
__global__ __launch_bounds__(256, 2) void gemm_ub_k(const float* __restrict__ u,
                                                    const unsigned short* __restrict__ Bb,
                                                    unsigned short* __restrict__ ubT) {
  __shared__ __align__(16) char smem[67584];  // 2x24KB staging / 66KB transpose
  const int tid = threadIdx.x, l = tid & 63, w = tid >> 6;
  const int wr = w >> 1, wc = w & 1, lr = l & 15, g = l >> 4;
  int m0, i0;
  swzgrid(blockIdx.x, m0, i0);
  f32x4 acc[8][4];
  #pragma unroll
  for (int mi = 0; mi < 8; ++mi)
    #pragma unroll
    for (int ni = 0; ni < 4; ++ni) acc[mi][ni] = (f32x4){0.f, 0.f, 0.f, 0.f};
  float4 pf[8];
  // prologue: k-step 0 (A via f32 regs, B via gload_lds), preload k-step 1 f32
  f32_issue(u, m0, 0, tid, pf);
  stageB(Bb, i0, 0, smem, w, l);
  f32_write(smem, tid, pf);           // reg-wait drains f32(0)
  f32_issue(u, m0, 32, tid, pf);
  for (int kt = 0; kt < 16; ++kt) {
    char* bufC = smem + (kt & 1) * GBUF;
    char* bufN = smem + ((kt + 1) & 1) * GBUF;
    if (kt < 15) stageB(Bb, i0, (kt + 1) * 32, bufN, w, l);
    if (kt < 15) BAR1(10); else BAR1(0);
    compute32(bufC, acc, wr, wc, lr, g);
    if (kt < 15) {
      f32_write(bufN, tid, pf);       // data for k-step kt+1
      if (kt < 14) f32_issue(u, m0, (kt + 2) * 32, tid, pf);
    }
    BAR2();
  }
  // epilogue: transposed tile T[i][m] (row stride 528B), then coalesced ubT
  #pragma unroll
  for (int mi = 0; mi < 8; ++mi)
    #pragma unroll
    for (int ni = 0; ni < 4; ++ni) {
      const int mb = wr * 128 + mi * 16 + g * 4;
      const int il = wc * 64 + ni * 16 + lr;
      uint2 v;
      v.x = pack_bf2(acc[mi][ni][0], acc[mi][ni][1]);
      v.y = pack_bf2(acc[mi][ni][2], acc[mi][ni][3]);
      *(uint2*)(smem + il * TROW + mb * 2) = v;
    }
  __syncthreads();
  const int iG = tid >> 1, sub = tid & 1, t0 = m0 >> 5;
  #pragma unroll
  for (int tl = 0; tl < 8; ++tl) {
    const char* sp = smem + iG * TROW + tl * 64 + sub * 32;
    short8 v0 = *(const short8*)(sp);
    short8 v1 = *(const short8*)(sp + 16);
    size_t base = (size_t)(t0 + tl) * TN + (size_t)(i0 + iG) * NBATCH + sub * 16;
    *(short8*)(ubT + base) = v0;
    *(short8*)(ubT + base + 8) = v1;
  }
}

// ---------------- K3: y = x_hist @ C^T + u @ D^T -> f32 ----------------
__global__ __launch_bounds__(256, 2) void gemm_y_k(const unsigned short* __restrict__ xh,
                                                   const float* __restrict__ u,
                                                   const unsigned short* __restrict__ Cb,
                                                   const unsigned short* __restrict__ Db,
                                                   float* __restrict__ y) {
  __shared__ __align__(16) char smem[2 * GBUF];
  const int tid = threadIdx.x, l = tid & 63, w = tid >> 6;
  const int wr = w >> 1, wc = w & 1, lr = l & 15, g = l >> 4;
  int m0, i0;
  swzgrid(blockIdx.x, m0, i0);
  f32x4 acc[8][4];
  #pragma unroll
  for (int mi = 0; mi < 8; ++mi)
    #pragma unroll
    for (int ni = 0; ni < 4; ++ni) acc[mi][ni] = (f32x4){0.f, 0.f, 0.f, 0.f};
  float4 pf[8];
  // prologue: k-step 0 (xh / Cb)
  stageA(xh, m0, 0, smem, w, l);
  stageB(Cb, i0, 0, smem, w, l);
  // K=1024 as 32 steps: kt<16 -> pass1 (xh/Cb), else pass2 (u/Db)
  for (int kt = 0; kt < 32; ++kt) {
    char* bufC = smem + (kt & 1) * GBUF;
    char* bufN = smem + ((kt + 1) & 1) * GBUF;
    if (kt < 15) {
      stageA(xh, m0, (kt + 1) * 32, bufN, w, l);
      stageB(Cb, i0, (kt + 1) * 32, bufN, w, l);
    } else if (kt < 31) {
      stageB(Db, i0, (kt + 1 - 16) * 32, bufN, w, l);
    }
    if (kt < 15) BAR1(6);
    else if (kt == 15) BAR1(10);
    else if (kt < 31) BAR1(10);
    else BAR1(0);
    compute32(bufC, acc, wr, wc, lr, g);
    if (kt == 14) {
      f32_issue(u, m0, 0, tid, pf);              // pf <- k-step 16 data
    } else if (kt >= 15 && kt < 31) {
      f32_write(bufN, tid, pf);                  // data for k-step kt+1
      if (kt < 30) f32_issue(u, m0, (kt + 2 - 16) * 32, tid, pf);
    }
    BAR2();
  }
  // epilogue: direct f32 stores (64B coalesced runs per 16-lane group)
  #pragma unroll
  for (int mi = 0; mi < 8; ++mi)
    #pragma unroll
    for (int ni = 0; ni < 4; ++ni) {
      const int ig = i0 + wc * 64 + ni * 16 + lr;
      const size_t mb = (size_t)(m0 + wr * 128 + mi * 16 + g * 4);
      #pragma unroll
      for (int r = 0; r < 4; ++r)
        y[(mb + r) * FD + ig] = acc[mi][ni][r];
    }
}

// ---------------- K2: chunked scan, 8 waves / group, padded LDS ------------
__global__ __launch_bounds__(512) void serial_k(const unsigned short* __restrict__ Ab,
                                                const unsigned short* __restrict__ ubT,
                                                unsigned short* __restrict__ xhist) {
  __shared__ __align__(16) unsigned char AldsB[512 * AROW];  // 139264 B
  __shared__ __align__(16) unsigned char xbufB[16 * XROW];   // 16640 B
  const int tid = threadIdx.x;
  const int l = tid & 63, w = tid >> 6;   // 8 waves; wave w owns cols [w*64,+64)
  const int lr = l & 15, g = l >> 4;      // g in 0..3
  const int b = blockIdx.x;
  const int chunk = b >> 1, nh = b & 1, n0 = nh * 16;
  const int tstart = chunk * CHUNK;
  const int t0 = (chunk == 0) ? 0 : tstart - WARM;
  const int nsteps = tstart + CHUNK - t0;

  // ---- A K<384 into registers: areg[4 col-tiles][12 k-frags] ----
  short8 areg[4][12];
  #pragma unroll
  for (int ct = 0; ct < 4; ++ct) {
    const int i = w * 64 + ct * 16 + lr;
    #pragma unroll
    for (int kb = 0; kb < 12; ++kb)
      areg[ct][kb] = *(const short8*)(Ab + (size_t)i * FD + kb * 32 + g * 8);
  }
  // ---- stage A[:, 384:512) into padded Alds (prologue only) ----
  for (int rr = 0; rr < 16; ++rr) {
    const int row = rr * 32 + (tid >> 4);   // 0..511
    const int kc = tid & 15;
    short8 v = *(const short8*)(Ab + (size_t)row * FD + KREG + kc * 8);
    *(short8*)(AldsB + row * AROW + kc * 16) = v;
  }
  BAR();

  // ---- incrementing bases with immediate offsets ----
  const unsigned short* ubp =
      ubT + (size_t)t0 * TN + (size_t)(w * 64 + lr) * NBATCH + n0 + g * 4;
  unsigned short* xhp =
      xhist + ((size_t)t0 * NBATCH + n0 + g * 4) * FD + w * 64 + lr;
  const unsigned char* xread = xbufB + lr * XROW + g * 16;             // +kb*64
  unsigned char* xwrite = xbufB + (g * 4) * XROW + (w * 64 + lr) * 2;  // +r*XROW+ct*32
  const unsigned char* aldsr[4];
  #pragma unroll
  for (int ct = 0; ct < 4; ++ct)
    aldsr[ct] = AldsB + (w * 64 + ct * 16 + lr) * AROW + g * 16;       // +kb2*64

  // ---- prologue ub prefetch ----
  short4v ubr[4];
  #pragma unroll
  for (int ct = 0; ct < 4; ++ct) ubr[ct] = *(const short4v*)(ubp + ct * 512);
  ubp += TN;

  for (int s = 0; s < nsteps; ++s) {
    const int t = t0 + s;
    f32x4 acc[4];
    #pragma unroll
    for (int ct = 0; ct < 4; ++ct)
      #pragma unroll
      for (int r = 0; r < 4; ++r) acc[ct][r] = bf2f((unsigned short)ubr[ct][r]);
    if (s + 1 < nsteps) {
      #pragma unroll
      for (int ct = 0; ct < 4; ++ct) ubr[ct] = *(const short4v*)(ubp + ct * 512);
    }
    ubp += TN;
    if (s > 0) {
      #pragma unroll
      for (int kb = 0; kb < 12; ++kb) {
        short8 xf = *(const short8*)(xread + kb * 64);
        #pragma unroll
        for (int ct = 0; ct < 4; ++ct) acc[ct] = mfma16(xf, areg[ct][kb], acc[ct]);
      }
      #pragma unroll
      for (int kb2 = 0; kb2 < 4; ++kb2) {
        short8 xf = *(const short8*)(xread + (12 + kb2) * 64);
        #pragma unroll
        for (int ct = 0; ct < 4; ++ct) {
          short8 af = *(const short8*)(aldsr[ct] + kb2 * 64);
          acc[ct] = mfma16(xf, af, acc[ct]);
        }
      }
    }
    // tanh -> bf16
    unsigned short hv[4][4];
    #pragma unroll
    for (int ct = 0; ct < 4; ++ct)
      #pragma unroll
      for (int r = 0; r < 4; ++r) {
        float e = __expf(2.f * acc[ct][r]);
        hv[ct][r] = f2bf_fast(1.f - 2.f * __builtin_amdgcn_rcpf(e + 1.f));
      }
    // xhist stores: fire-and-forget (no vmcnt drain at barriers)
    if (t >= tstart) {
      #pragma unroll
      for (int ct = 0; ct < 4; ++ct)
        #pragma unroll
        for (int r = 0; r < 4; ++r) xhp[r * FD + ct * 16] = hv[ct][r];
    }
    xhp += (size_t)NBATCH * FD;
    BAR();  // all xbuf reads of this step done (lgkm only)
    #pragma unroll
    for (int ct = 0; ct < 4; ++ct)
      #pragma unroll
      for (int r = 0; r < 4; ++r)
        *(unsigned short*)(xwrite + r * XROW + ct * 32) = hv[ct][r];
    BAR();  // xbuf writes visible before next step's reads
  }
}

// ---------------- launch ----------------
extern "C" void kernel_launch(void* const* d_in, const int* in_sizes, int n_in,
                              void* d_out, int out_size, void* d_ws, size_t ws_size,
                              hipStream_t stream) {
  const float* u = (const float*)d_in[0];
  const float* A = (const float*)d_in[1];
  const float* B = (const float*)d_in[2];
  const float* C = (const float*)d_in[3];
  const float* D = (const float*)d_in[4];
  float* y = (float*)d_out;

  char* ws = (char*)d_ws;
  size_t off = 0;
  unsigned short* ubT = (unsigned short*)(ws + off);   off += (size_t)M_TOT * FD * 2;
  unsigned short* xhist = (unsigned short*)(ws + off); off += (size_t)M_TOT * FD * 2;
  unsigned short* Ab = (unsigned short*)(ws + off);    off += (size_t)FD * FD * 2;
  unsigned short* Bb = (unsigned short*)(ws + off);    off += (size_t)FD * FD * 2;
  unsigned short* Cb = (unsigned short*)(ws + off);    off += (size_t)FD * FD * 2;
  unsigned short* Db = (unsigned short*)(ws + off);    off += (size_t)FD * FD * 2;

  cvt_k<<<dim3(FD * FD / (256 * 4), 4), 256, 0, stream>>>(A, B, C, D, Ab, Bb, Cb, Db);
  gemm_ub_k<<<dim3(NWGG, 1), 256, 0, stream>>>(u, Bb, ubT);
  serial_k<<<dim3(NGRP, 1), 512, 0, stream>>>(Ab, ubT, xhist);
  gemm_y_k<<<dim3(NWGG, 1), 256, 0, stream>>>(xhist, u, Cb, Db, y);
}

// Round 11
// 598.600 us; speedup vs baseline: 1.0692x; 1.0692x over previous
//
#include <hip/hip_runtime.h>

// ============================================================================
// Elman tanh-SSM: x_t = tanh(x_{t-1}A^T + u_t B^T); y_t = x_t C^T + u_t D^T
// T=4096, N=32, F=512, f32 in/out.
//
//  K0: convert A,B,C,D -> bf16
//  K1: ubT = (u @ B^T) transposed [t][i][n]
//  K2: chunked-parallel scan -> x_hist bf16 (unchanged from round 5)
//  K3: y = x_hist @ C^T + u @ D^T
//
// GEMM = round-8 geometry exactly (256x128, BK=64, 512 thr, per-wave 64x64
// acc[4][4], VGPR~104 no spill, two 32-k panels 64B rows + chunk-XOR
// swizzle both sides). ONE change vs round 8: __syncthreads (vmcnt(0)
// drain) -> two raw barriers with COUNTED vmcnt so next-tile loads stay in
// flight across the barrier (T3/T4; round-10's version of this was
// confounded by an acc[8][4] spill).  BAR1(N) = "all but the N most recent
// VMEM issues are complete" -> N = issues after the stage being waited on,
// derived from in-order VMEM completion. BAR2 = raw s_barrier (ds_reads
// are compiler-forced complete before the preceding MFMAs).
// ============================================================================

typedef unsigned int u32;
typedef __attribute__((ext_vector_type(8))) short short8;
typedef __attribute__((ext_vector_type(4))) short short4v;
typedef __attribute__((ext_vector_type(4))) float f32x4;

#define AS1 __attribute__((address_space(1)))
#define AS3 __attribute__((address_space(3)))

static constexpr int TT     = 4096;
static constexpr int NBATCH = 32;
static constexpr int FD     = 512;
static constexpr int M_TOT  = TT * NBATCH;   // 131072
static constexpr int CHUNK  = 32;
static constexpr int WARM   = 32;
static constexpr int NCHUNK = TT / CHUNK;    // 128
static constexpr int NGRP   = NCHUNK * 2;    // 256 (x2 batch halves)
static constexpr int KREG   = 384;           // serial_k: K-range in registers
static constexpr int TN     = FD * NBATCH;   // 16384 (ubT t-stride)
static constexpr int NWGG   = (M_TOT / 256) * (FD / 128);  // 2048

static constexpr int XROW = 1040;            // serial xbuf row stride bytes
static constexpr int AROW = 272;             // serial Alds row stride bytes
static constexpr int TROW = 528;             // ub transpose row stride bytes
// GEMM LDS: per buffer A 2x16KB panels + B 2x8KB panels = 48KB; x2 = 96KB
static constexpr int BUFSZ = 49152;
static constexpr int BOFF  = 32768;

// raw barrier: LDS visibility only (serial_k)
#define BAR() asm volatile("s_waitcnt lgkmcnt(0)\n\ts_barrier" ::: "memory")
// GEMM barriers: counted vmcnt + lgkm flush / raw close
#define BAR1(N) do { \
    asm volatile("s_waitcnt vmcnt(" #N ") lgkmcnt(0)\n\ts_barrier" ::: "memory"); \
    __builtin_amdgcn_sched_barrier(0); } while (0)
#define BAR2() do { __builtin_amdgcn_sched_barrier(0); \
    asm volatile("s_barrier" ::: "memory"); } while (0)

// ---------------- helpers ----------------
__device__ __forceinline__ unsigned short f2bf(float f) {
  u32 u = __builtin_bit_cast(u32, f);
  u32 r = u + 0x7FFFu + ((u >> 16) & 1u);   // RTNE
  return (unsigned short)(r >> 16);
}
__device__ __forceinline__ unsigned short f2bf_fast(float f) {  // half-up
  u32 u = __builtin_bit_cast(u32, f);
  return (unsigned short)((u + 0x8000u) >> 16);
}
__device__ __forceinline__ float bf2f(unsigned short h) {
  u32 u = ((u32)h) << 16;
  return __builtin_bit_cast(float, u);
}
__device__ __forceinline__ u32 pack_bf2(float a, float b) {  // cvt_pk
  __bf16 x = (__bf16)a, y = (__bf16)b;
  return (u32)__builtin_bit_cast(unsigned short, x) |
         ((u32)__builtin_bit_cast(unsigned short, y) << 16);
}

typedef __attribute__((ext_vector_type(8))) __bf16 bf16x8;
__device__ __forceinline__ f32x4 mfma16(short8 a, short8 b, f32x4 c) {
  return __builtin_amdgcn_mfma_f32_16x16x32_bf16(
      __builtin_bit_cast(bf16x8, a), __builtin_bit_cast(bf16x8, b), c, 0, 0, 0);
}

// ---------------- K0: convert A,B,C,D to bf16 ----------------
__global__ void cvt_k(const float* __restrict__ A, const float* __restrict__ B,
                      const float* __restrict__ C, const float* __restrict__ D,
                      unsigned short* __restrict__ Ab, unsigned short* __restrict__ Bb,
                      unsigned short* __restrict__ Cb, unsigned short* __restrict__ Db) {
  const float* s;
  unsigned short* d;
  switch (blockIdx.y) {
    case 0: s = A; d = Ab; break;
    case 1: s = B; d = Bb; break;
    case 2: s = C; d = Cb; break;
    default: s = D; d = Db; break;
  }
  int i = (blockIdx.x * blockDim.x + threadIdx.x) * 4;
  float4 f = *(const float4*)(s + i);
  short4v v;
  v[0] = (short)f2bf(f.x); v[1] = (short)f2bf(f.y);
  v[2] = (short)f2bf(f.z); v[3] = (short)f2bf(f.w);
  *(short4v*)(d + i) = v;
}

// ---------------- 256x128 BK=64 GEMM building blocks (512 threads) ---------
// A-tile: 2 panels [256 rows][32k] (64B rows) at buf + h*16384.
// B-tile: 2 panels [128 rows][32k] at buf + BOFF + h*8192.
// Chunk-XOR: LDS[row][c] holds global chunk c ^ (row&3)  (16B chunks).

__device__ __forceinline__ void stage_a_bf16(const unsigned short* __restrict__ src,
                                             int row0, int k0, char* aBase,
                                             int w, int l) {
  const int rsub = l >> 2;
  const int csw = ((l & 3) ^ (rsub & 3)) * 8;  // pre-swizzled source chunk
  #pragma unroll
  for (int h = 0; h < 2; ++h)
    #pragma unroll
    for (int j = 0; j < 2; ++j) {
      const int rb = (w * 2 + j) * 16;
      const unsigned short* gp =
          src + (size_t)(row0 + rb + rsub) * FD + k0 + h * 32 + csw;
      __builtin_amdgcn_global_load_lds((const AS1 u32*)gp,
                                       (AS3 u32*)(aBase + h * 16384 + rb * 64), 16, 0, 0);
    }
}
__device__ __forceinline__ void stage_b_bf16(const unsigned short* __restrict__ src,
                                             int row0, int k0, char* bBase,
                                             int w, int l) {
  const int rsub = l >> 2;
  const int csw = ((l & 3) ^ (rsub & 3)) * 8;
  #pragma unroll
  for (int h = 0; h < 2; ++h) {
    const unsigned short* gp =
        src + (size_t)(row0 + w * 16 + rsub) * FD + k0 + h * 32 + csw;
    __builtin_amdgcn_global_load_lds((const AS1 u32*)gp,
                                     (AS3 u32*)(bBase + BOFF + h * 8192 + w * 1024), 16, 0, 0);
  }
}

__device__ __forceinline__ void f32_issue(const float* __restrict__ src, int m0,
                                          int k0, int tid, float4 (&pf)[8]) {
  const int rsub = tid >> 4, c = tid & 15;
  #pragma unroll
  for (int q = 0; q < 8; ++q)
    pf[q] = *(const float4*)(src + (size_t)(m0 + q * 32 + rsub) * FD + k0 + c * 4);
}
__device__ __forceinline__ void f32_write(char* aBase, int tid, float4 (&pf)[8]) {
  const int rsub = tid >> 4, c = tid & 15;
  const int h = c >> 3, gc = (c >> 1) & 3, half = (c & 1) * 8;
  #pragma unroll
  for (int q = 0; q < 8; ++q) {
    const int row = q * 32 + rsub;
    uint2 v;
    v.x = pack_bf2(pf[q].x, pf[q].y);
    v.y = pack_bf2(pf[q].z, pf[q].w);
    *(uint2*)(aBase + h * 16384 + row * 64 + (gc ^ (row & 3)) * 16 + half) = v;
  }
}

__device__ __forceinline__ void compute64(const char* aBase, f32x4 (&acc)[4][4],
                                          int wr, int wc, int lr, int g) {
  const int co = (g ^ (lr & 3)) * 16;  // swizzled read chunk
  #pragma unroll
  for (int h = 0; h < 2; ++h) {
    short8 af[4], bf[4];
    #pragma unroll
    for (int mi = 0; mi < 4; ++mi)
      af[mi] = *(const short8*)(aBase + h * 16384 + (wr * 64 + mi * 16 + lr) * 64 + co);
    #pragma unroll
    for (int ni = 0; ni < 4; ++ni)
      bf[ni] = *(const short8*)(aBase + BOFF + h * 8192 + (wc * 64 + ni * 16 + lr) * 64 + co);
    __builtin_amdgcn_s_setprio(1);
    #pragma unroll
    for (int mi = 0; mi < 4; ++mi)
      #pragma unroll
      for (int ni = 0; ni < 4; ++ni)
        acc[mi][ni] = mfma16(af[mi], bf[ni], acc[mi][ni]);
    __builtin_amdgcn_s_setprio(0);
  }
}

__device__ __forceinline__ void swzgrid(int bid, int& m0, int& i0) {
  int wg = (bid & 7) * (NWGG >> 3) + (bid >> 3);  // XCD-contiguous, bijective
  m0 = (wg >> 2) * 256;                           // n-fastest: 4 i-blocks of an
  i0 = (wg & 3) * 128;                            // m-panel share one L2
}

// ---------------- K1: ubT[t][i][n] = (u @ B^T) -> bf16 transposed ----------
__global__ __launch_bounds__(512) void gemm_ub_k(const float* __restrict__ u,
                                                 const unsigned short* __restrict__ Bb,
                                                 unsigned short* __restrict__ ubT) {
  __shared__ __align__(16) char smem[98304];
  const int tid = threadIdx.x, l = tid & 63, w = tid >> 6;
  const int wr = w >> 1, wc = w & 1, lr = l & 15, g = l >> 4;
  int m0, i0;
  swzgrid(blockIdx.x, m0, i0);
  f32x4 acc[4][4];
  #pragma unroll
  for (int mi = 0; mi < 4; ++mi)
    #pragma unroll
    for (int ni = 0; ni < 4; ++ni) acc[mi][ni] = (f32x4){0.f, 0.f, 0.f, 0.f};
  float4 pf[8];
  // prologue: step-0 A (f32 regs -> LDS), step-0 B, then step-1 f32 issue
  f32_issue(u, m0, 0, tid, pf);        // 8 (drained by f32_write reg-dep)
  stage_b_bf16(Bb, i0, 0, smem, w, l); // 2
  f32_write(smem, tid, pf);
  f32_issue(u, m0, 64, tid, pf);       // 8 (step-1 data)
  int cur = 0;
  for (int kt = 0; kt < 8; ++kt) {
    char* aCur = smem + cur * BUFSZ;
    char* aNxt = smem + (cur ^ 1) * BUFSZ;
    if (kt < 7) {
      stage_b_bf16(Bb, i0, (kt + 1) * 64, aNxt, w, l);  // 2
      BAR1(10);  // after prev B-stage: prev f32_issue(8) + this B-stage(2)
    } else {
      BAR1(0);
    }
    compute64(aCur, acc, wr, wc, lr, g);
    if (kt < 7) {
      f32_write(aNxt, tid, pf);        // step kt+1 A-data (reg-dep drains pf)
      if (kt < 6) f32_issue(u, m0, (kt + 2) * 64, tid, pf);
    }
    BAR2();
    cur ^= 1;
  }
  // epilogue: transposed tile T[i][m] (row stride 528B), then coalesced ubT
  #pragma unroll
  for (int mi = 0; mi < 4; ++mi)
    #pragma unroll
    for (int ni = 0; ni < 4; ++ni) {
      const int mb = wr * 64 + mi * 16 + g * 4;
      const int il = wc * 64 + ni * 16 + lr;
      uint2 v;
      v.x = pack_bf2(acc[mi][ni][0], acc[mi][ni][1]);
      v.y = pack_bf2(acc[mi][ni][2], acc[mi][ni][3]);
      *(uint2*)(smem + il * TROW + mb * 2) = v;
    }
  __syncthreads();
  const int iG = tid >> 2, sub = tid & 3, t0 = m0 >> 5;
  #pragma unroll
  for (int tl = 0; tl < 8; ++tl) {
    short8 v = *(const short8*)(smem + iG * TROW + (tl * 32 + sub * 8) * 2);
    *(short8*)(ubT + (size_t)(t0 + tl) * TN + (size_t)(i0 + iG) * NBATCH + sub * 8) = v;
  }
}

// ---------------- K3: y = x_hist @ C^T + u @ D^T -> f32 ----------------
__global__ __launch_bounds__(512) void gemm_y_k(const unsigned short* __restrict__ xh,
                                                const float* __restrict__ u,
                                                const unsigned short* __restrict__ Cb,
                                                const unsigned short* __restrict__ Db,
                                                float* __restrict__ y) {
  __shared__ __align__(16) char smem[98304];
  const int tid = threadIdx.x, l = tid & 63, w = tid >> 6;
  const int wr = w >> 1, wc = w & 1, lr = l & 15, g = l >> 4;
  int m0, i0;
  swzgrid(blockIdx.x, m0, i0);
  f32x4 acc[4][4];
  #pragma unroll
  for (int mi = 0; mi < 4; ++mi)
    #pragma unroll
    for (int ni = 0; ni < 4; ++ni) acc[mi][ni] = (f32x4){0.f, 0.f, 0.f, 0.f};
  float4 pf[8];
  // prologue: step-0 tiles (xh / Cb)
  stage_a_bf16(xh, m0, 0, smem, w, l);  // 4
  stage_b_bf16(Cb, i0, 0, smem, w, l);  // 2
  int cur = 0;
  // 16 K-tiles of 64: kt<8 -> pass1 (xh/Cb), kt>=8 -> pass2 (u/Db)
  for (int kt = 0; kt < 16; ++kt) {
    char* aCur = smem + cur * BUFSZ;
    char* aNxt = smem + (cur ^ 1) * BUFSZ;
    if (kt < 7) {
      stage_a_bf16(xh, m0, (kt + 1) * 64, aNxt, w, l);  // 4
      stage_b_bf16(Cb, i0, (kt + 1) * 64, aNxt, w, l);  // 2
      BAR1(6);   // after prev 6-stage: this iter's 6
    } else if (kt == 7) {
      stage_b_bf16(Db, i0, 0, aNxt, w, l);              // 2 (B stage FIRST)
      f32_issue(u, m0, 0, tid, pf);                     // 8 (step-8 A data)
      BAR1(10);  // after prev 6-stage: 2 + 8
    } else if (kt < 15) {
      stage_b_bf16(Db, i0, (kt + 1 - 8) * 64, aNxt, w, l);  // 2
      BAR1(10);  // after prev B-stage: prev f32_issue(8) + this B-stage(2)
    } else {
      BAR1(0);
    }
    compute64(aCur, acc, wr, wc, lr, g);
    if (kt >= 7 && kt < 15) {
      f32_write(aNxt, tid, pf);        // step kt+1 A-data
      if (kt < 14) f32_issue(u, m0, (kt + 2 - 8) * 64, tid, pf);
    }
    BAR2();
    cur ^= 1;
  }
  // epilogue: direct f32 stores (64B coalesced runs per 16-lane group)
  #pragma unroll
  for (int mi = 0; mi < 4; ++mi)
    #pragma unroll
    for (int ni = 0; ni < 4; ++ni) {
      const int ig = i0 + wc * 64 + ni * 16 + lr;
      const size_t mb = (size_t)(m0 + wr * 64 + mi * 16 + g * 4);
      #pragma unroll
      for (int r = 0; r < 4; ++r)
        y[(mb + r) * FD + ig] = acc[mi][ni][r];
    }
}

// ---------------- K2: chunked scan, 8 waves / group, padded LDS ------------
__global__ __launch_bounds__(512) void serial_k(const unsigned short* __restrict__ Ab,
                                                const unsigned short* __restrict__ ubT,
                                                unsigned short* __restrict__ xhist) {
  __shared__ __align__(16) unsigned char AldsB[512 * AROW];  // 139264 B
  __shared__ __align__(16) unsigned char xbufB[16 * XROW];   // 16640 B
  const int tid = threadIdx.x;
  const int l = tid & 63, w = tid >> 6;   // 8 waves; wave w owns cols [w*64,+64)
  const int lr = l & 15, g = l >> 4;      // g in 0..3
  const int b = blockIdx.x;
  const int chunk = b >> 1, nh = b & 1, n0 = nh * 16;
  const int tstart = chunk * CHUNK;
  const int t0 = (chunk == 0) ? 0 : tstart - WARM;
  const int nsteps = tstart + CHUNK - t0;

  // ---- A K<384 into registers: areg[4 col-tiles][12 k-frags] ----
  short8 areg[4][12];
  #pragma unroll
  for (int ct = 0; ct < 4; ++ct) {
    const int i = w * 64 + ct * 16 + lr;
    #pragma unroll
    for (int kb = 0; kb < 12; ++kb)
      areg[ct][kb] = *(const short8*)(Ab + (size_t)i * FD + kb * 32 + g * 8);
  }
  // ---- stage A[:, 384:512) into padded Alds (prologue only) ----
  for (int rr = 0; rr < 16; ++rr) {
    const int row = rr * 32 + (tid >> 4);   // 0..511
    const int kc = tid & 15;
    short8 v = *(const short8*)(Ab + (size_t)row * FD + KREG + kc * 8);
    *(short8*)(AldsB + row * AROW + kc * 16) = v;
  }
  BAR();

  // ---- incrementing bases with immediate offsets ----
  const unsigned short* ubp =
      ubT + (size_t)t0 * TN + (size_t)(w * 64 + lr) * NBATCH + n0 + g * 4;
  unsigned short* xhp =
      xhist + ((size_t)t0 * NBATCH + n0 + g * 4) * FD + w * 64 + lr;
  const unsigned char* xread = xbufB + lr * XROW + g * 16;             // +kb*64
  unsigned char* xwrite = xbufB + (g * 4) * XROW + (w * 64 + lr) * 2;  // +r*XROW+ct*32
  const unsigned char* aldsr[4];
  #pragma unroll
  for (int ct = 0; ct < 4; ++ct)
    aldsr[ct] = AldsB + (w * 64 + ct * 16 + lr) * AROW + g * 16;       // +kb2*64

  // ---- prologue ub prefetch ----
  short4v ubr[4];
  #pragma unroll
  for (int ct = 0; ct < 4; ++ct) ubr[ct] = *(const short4v*)(ubp + ct * 512);
  ubp += TN;

  for (int s = 0; s < nsteps; ++s) {
    const int t = t0 + s;
    f32x4 acc[4];
    #pragma unroll
    for (int ct = 0; ct < 4; ++ct)
      #pragma unroll
      for (int r = 0; r < 4; ++r) acc[ct][r] = bf2f((unsigned short)ubr[ct][r]);
    if (s + 1 < nsteps) {
      #pragma unroll
      for (int ct = 0; ct < 4; ++ct) ubr[ct] = *(const short4v*)(ubp + ct * 512);
    }
    ubp += TN;
    if (s > 0) {
      #pragma unroll
      for (int kb = 0; kb < 12; ++kb) {
        short8 xf = *(const short8*)(xread + kb * 64);
        #pragma unroll
        for (int ct = 0; ct < 4; ++ct) acc[ct] = mfma16(xf, areg[ct][kb], acc[ct]);
      }
      #pragma unroll
      for (int kb2 = 0; kb2 < 4; ++kb2) {
        short8 xf = *(const short8*)(xread + (12 + kb2) * 64);
        #pragma unroll
        for (int ct = 0; ct < 4; ++ct) {
          short8 af = *(const short8*)(aldsr[ct] + kb2 * 64);
          acc[ct] = mfma16(xf, af, acc[ct]);
        }
      }
    }
    // tanh -> bf16
    unsigned short hv[4][4];
    #pragma unroll
    for (int ct = 0; ct < 4; ++ct)
      #pragma unroll
      for (int r = 0; r < 4; ++r) {
        float e = __expf(2.f * acc[ct][r]);
        hv[ct][r] = f2bf_fast(1.f - 2.f * __builtin_amdgcn_rcpf(e + 1.f));
      }
    // xhist stores: fire-and-forget (no vmcnt drain at barriers)
    if (t >= tstart) {
      #pragma unroll
      for (int ct = 0; ct < 4; ++ct)
        #pragma unroll
        for (int r = 0; r < 4; ++r) xhp[r * FD + ct * 16] = hv[ct][r];
    }
    xhp += (size_t)NBATCH * FD;
    BAR();  // all xbuf reads of this step done (lgkm only)
    #pragma unroll
    for (int ct = 0; ct < 4; ++ct)
      #pragma unroll
      for (int r = 0; r < 4; ++r)
        *(unsigned short*)(xwrite + r * XROW + ct * 32) = hv[ct][r];
    BAR();  // xbuf writes visible before next step's reads
  }
}

// ---------------- launch ----------------
extern "C" void kernel_launch(void* const* d_in, const int* in_sizes, int n_in,
                              void* d_out, int out_size, void* d_ws, size_t ws_size,
                              hipStream_t stream) {
  const float* u = (const float*)d_in[0];
  const float* A = (const float*)d_in[1];
  const float* B = (const float*)d_in[2];
  const float* C = (const float*)d_in[3];
  const float* D = (const float*)d_in[4];
  float* y = (float*)d_out;

  char* ws = (char*)d_ws;
  size_t off = 0;
  unsigned short* ubT = (unsigned short*)(ws + off);   off += (size_t)M_TOT * FD * 2;
  unsigned short* xhist = (unsigned short*)(ws + off); off += (size_t)M_TOT * FD * 2;
  unsigned short* Ab = (unsigned short*)(ws + off);    off += (size_t)FD * FD * 2;
  unsigned short* Bb = (unsigned short*)(ws + off);    off += (size_t)FD * FD * 2;
  unsigned short* Cb = (unsigned short*)(ws + off);    off += (size_t)FD * FD * 2;
  unsigned short* Db = (unsigned short*)(ws + off);    off += (size_t)FD * FD * 2;

  cvt_k<<<dim3(FD * FD / (256 * 4), 4), 256, 0, stream>>>(A, B, C, D, Ab, Bb, Cb, Db);
  gemm_ub_k<<<dim3(NWGG, 1), 512, 0, stream>>>(u, Bb, ubT);
  serial_k<<<dim3(NGRP, 1), 512, 0, stream>>>(Ab, ubT, xhist);
  gemm_y_k<<<dim3(NWGG, 1), 512, 0, stream>>>(xhist, u, Cb, Db, y);
}

// Round 12
// 567.193 us; speedup vs baseline: 1.1284x; 1.0554x over previous
//
#include <hip/hip_runtime.h>

// ============================================================================
// Elman tanh-SSM: x_t = tanh(x_{t-1}A^T + u_t B^T); y_t = x_t C^T + u_t D^T
// T=4096, N=32, F=512, f32 in/out.
//
//  K0: convert A,B,C,D -> bf16
//  K1: ubT = (u @ B^T) transposed [t][i][n]
//  K2: chunked-parallel scan -> x_hist bf16 (unchanged from round 5)
//  K3: y = x_hist @ C^T + u @ D^T
//
// Round-12 GEMM: same proven tile math as rounds 8/11 (256x128, acc[4][4],
// 64B LDS rows + chunk-XOR swizzle both sides, VGPR ~100 no spill) but
// BK 64->32 so dbuf LDS = 48KB -> TWO WGs/CU (launch_bounds(512,4)).
// Round-11 showed counted-vmcnt at coarse 2-phase = null (regime-gate:
// T4 needs 8-phase) and 1 WG/CU leaves Occ 23% / all pipes <21%. The
// lever is cross-WG TLP: two counter-phase WGs hide each other's barrier
// drains. Sync = ONE plain __syncthreads per K-step (round-8 scheme).
// SQ_LDS_BANK_CONFLICT ~2e7 diagnosed as inherent b128 multi-cycle
// returns (uniform bank-quad distribution = floor) - not actionable.
// ============================================================================

typedef unsigned int u32;
typedef __attribute__((ext_vector_type(8))) short short8;
typedef __attribute__((ext_vector_type(4))) short short4v;
typedef __attribute__((ext_vector_type(4))) float f32x4;

#define AS1 __attribute__((address_space(1)))
#define AS3 __attribute__((address_space(3)))

static constexpr int TT     = 4096;
static constexpr int NBATCH = 32;
static constexpr int FD     = 512;
static constexpr int M_TOT  = TT * NBATCH;   // 131072
static constexpr int CHUNK  = 32;
static constexpr int WARM   = 32;
static constexpr int NCHUNK = TT / CHUNK;    // 128
static constexpr int NGRP   = NCHUNK * 2;    // 256 (x2 batch halves)
static constexpr int KREG   = 384;           // serial_k: K-range in registers
static constexpr int TN     = FD * NBATCH;   // 16384 (ubT t-stride)
static constexpr int NWGG   = (M_TOT / 256) * (FD / 128);  // 2048

static constexpr int XROW = 1040;            // serial xbuf row stride bytes
static constexpr int AROW = 272;             // serial Alds row stride bytes
static constexpr int TROW = 528;             // ub transpose row stride bytes
// GEMM LDS buffer (BK=32): A [256][32k] 16KB @ +0; B [128][32k] 8KB @ +16384
static constexpr int GBUF = 24576;
static constexpr int BOFF = 16384;

// raw barrier: LDS visibility only (serial_k)
#define BAR() asm volatile("s_waitcnt lgkmcnt(0)\n\ts_barrier" ::: "memory")

// ---------------- helpers ----------------
__device__ __forceinline__ unsigned short f2bf(float f) {
  u32 u = __builtin_bit_cast(u32, f);
  u32 r = u + 0x7FFFu + ((u >> 16) & 1u);   // RTNE
  return (unsigned short)(r >> 16);
}
__device__ __forceinline__ unsigned short f2bf_fast(float f) {  // half-up
  u32 u = __builtin_bit_cast(u32, f);
  return (unsigned short)((u + 0x8000u) >> 16);
}
__device__ __forceinline__ float bf2f(unsigned short h) {
  u32 u = ((u32)h) << 16;
  return __builtin_bit_cast(float, u);
}
__device__ __forceinline__ u32 pack_bf2(float a, float b) {  // cvt_pk
  __bf16 x = (__bf16)a, y = (__bf16)b;
  return (u32)__builtin_bit_cast(unsigned short, x) |
         ((u32)__builtin_bit_cast(unsigned short, y) << 16);
}

typedef __attribute__((ext_vector_type(8))) __bf16 bf16x8;
__device__ __forceinline__ f32x4 mfma16(short8 a, short8 b, f32x4 c) {
  return __builtin_amdgcn_mfma_f32_16x16x32_bf16(
      __builtin_bit_cast(bf16x8, a), __builtin_bit_cast(bf16x8, b), c, 0, 0, 0);
}

// ---------------- K0: convert A,B,C,D to bf16 ----------------
__global__ void cvt_k(const float* __restrict__ A, const float* __restrict__ B,
                      const float* __restrict__ C, const float* __restrict__ D,
                      unsigned short* __restrict__ Ab, unsigned short* __restrict__ Bb,
                      unsigned short* __restrict__ Cb, unsigned short* __restrict__ Db) {
  const float* s;
  unsigned short* d;
  switch (blockIdx.y) {
    case 0: s = A; d = Ab; break;
    case 1: s = B; d = Bb; break;
    case 2: s = C; d = Cb; break;
    default: s = D; d = Db; break;
  }
  int i = (blockIdx.x * blockDim.x + threadIdx.x) * 4;
  float4 f = *(const float4*)(s + i);
  short4v v;
  v[0] = (short)f2bf(f.x); v[1] = (short)f2bf(f.y);
  v[2] = (short)f2bf(f.z); v[3] = (short)f2bf(f.w);
  *(short4v*)(d + i) = v;
}

// ---------------- 256x128 BK=32 GEMM building blocks (512 threads) ---------
// Chunk-XOR: LDS[row][c] holds global chunk c ^ (row&3)  (16B chunks, 64B rows).

__device__ __forceinline__ void stage_a_bf16(const unsigned short* __restrict__ src,
                                             int row0, int k0, char* buf,
                                             int w, int l) {
  const int rsub = l >> 2;
  const int csw = ((l & 3) ^ (rsub & 3)) * 8;  // pre-swizzled source chunk
  #pragma unroll
  for (int j = 0; j < 2; ++j) {
    const int q = w * 2 + j;  // 16 issues x 1KB = 16KB
    const unsigned short* gp =
        src + (size_t)(row0 + q * 16 + rsub) * FD + k0 + csw;
    __builtin_amdgcn_global_load_lds((const AS1 u32*)gp,
                                     (AS3 u32*)(buf + q * 1024), 16, 0, 0);
  }
}
__device__ __forceinline__ void stage_b_bf16(const unsigned short* __restrict__ src,
                                             int row0, int k0, char* buf,
                                             int w, int l) {
  const int rsub = l >> 2;
  const int csw = ((l & 3) ^ (rsub & 3)) * 8;
  const unsigned short* gp =
      src + (size_t)(row0 + w * 16 + rsub) * FD + k0 + csw;
  __builtin_amdgcn_global_load_lds((const AS1 u32*)gp,
                                   (AS3 u32*)(buf + BOFF + w * 1024), 16, 0, 0);
}

// f32 A-operand: 4 float4/thread (issue) -> bf16-pack LDS write (write)
__device__ __forceinline__ void f32_issue(const float* __restrict__ src, int m0,
                                          int k0, int tid, float4 (&pf)[4]) {
  const int rsub = tid >> 3, c = tid & 7;
  #pragma unroll
  for (int q = 0; q < 4; ++q)
    pf[q] = *(const float4*)(src + (size_t)(m0 + q * 64 + rsub) * FD + k0 + c * 4);
}
__device__ __forceinline__ void f32_write(char* buf, int tid, float4 (&pf)[4]) {
  const int rsub = tid >> 3, c = tid & 7;
  const int ch = c >> 1, half = (c & 1) * 8;
  #pragma unroll
  for (int q = 0; q < 4; ++q) {
    const int row = q * 64 + rsub;
    uint2 v;
    v.x = pack_bf2(pf[q].x, pf[q].y);
    v.y = pack_bf2(pf[q].z, pf[q].w);
    *(uint2*)(buf + row * 64 + (ch ^ (row & 3)) * 16 + half) = v;
  }
}

__device__ __forceinline__ void compute32(const char* buf, f32x4 (&acc)[4][4],
                                          int wr, int wc, int lr, int g) {
  const int co = (g ^ (lr & 3)) * 16;  // swizzled read chunk
  short8 af[4], bf[4];
  #pragma unroll
  for (int mi = 0; mi < 4; ++mi)
    af[mi] = *(const short8*)(buf + (wr * 64 + mi * 16 + lr) * 64 + co);
  #pragma unroll
  for (int ni = 0; ni < 4; ++ni)
    bf[ni] = *(const short8*)(buf + BOFF + (wc * 64 + ni * 16 + lr) * 64 + co);
  __builtin_amdgcn_s_setprio(1);
  #pragma unroll
  for (int mi = 0; mi < 4; ++mi)
    #pragma unroll
    for (int ni = 0; ni < 4; ++ni)
      acc[mi][ni] = mfma16(af[mi], bf[ni], acc[mi][ni]);
  __builtin_amdgcn_s_setprio(0);
}

__device__ __forceinline__ void swzgrid(int bid, int& m0, int& i0) {
  int wg = (bid & 7) * (NWGG >> 3) + (bid >> 3);  // XCD-contiguous, bijective
  m0 = (wg >> 2) * 256;                           // n-fastest: 4 i-blocks of an
  i0 = (wg & 3) * 128;                            // m-panel share one L2
}

// ---------------- K1: ubT[t][i][n] = (u @ B^T) -> bf16 transposed ----------
__global__ __launch_bounds__(512, 4) void gemm_ub_k(const float* __restrict__ u,
                                                    const unsigned short* __restrict__ Bb,
                                                    unsigned short* __restrict__ ubT) {
  __shared__ __align__(16) char smem[67584];  // 48KB staging / 66KB transpose
  const int tid = threadIdx.x, l = tid & 63, w = tid >> 6;
  const int wr = w >> 1, wc = w & 1, lr = l & 15, g = l >> 4;
  int m0, i0;
  swzgrid(blockIdx.x, m0, i0);
  f32x4 acc[4][4];
  #pragma unroll
  for (int mi = 0; mi < 4; ++mi)
    #pragma unroll
    for (int ni = 0; ni < 4; ++ni) acc[mi][ni] = (f32x4){0.f, 0.f, 0.f, 0.f};
  float4 pf[4];
  // prologue: step-0 A (f32->LDS) + B, then step-1 f32 issue
  f32_issue(u, m0, 0, tid, pf);
  stage_b_bf16(Bb, i0, 0, smem, w, l);
  f32_write(smem, tid, pf);
  f32_issue(u, m0, 32, tid, pf);
  __syncthreads();
  for (int kt = 0; kt < 16; ++kt) {
    char* bufC = smem + (kt & 1) * GBUF;
    char* bufN = smem + ((kt + 1) & 1) * GBUF;
    if (kt < 15) stage_b_bf16(Bb, i0, (kt + 1) * 32, bufN, w, l);
    compute32(bufC, acc, wr, wc, lr, g);
    if (kt < 15) {
      f32_write(bufN, tid, pf);   // data for step kt+1 (reg-dep drains pf)
      if (kt < 14) f32_issue(u, m0, (kt + 2) * 32, tid, pf);
    }
    __syncthreads();
  }
  // epilogue: transposed tile T[i][m] (row stride 528B), then coalesced ubT
  #pragma unroll
  for (int mi = 0; mi < 4; ++mi)
    #pragma unroll
    for (int ni = 0; ni < 4; ++ni) {
      const int mb = wr * 64 + mi * 16 + g * 4;
      const int il = wc * 64 + ni * 16 + lr;
      uint2 v;
      v.x = pack_bf2(acc[mi][ni][0], acc[mi][ni][1]);
      v.y = pack_bf2(acc[mi][ni][2], acc[mi][ni][3]);
      *(uint2*)(smem + il * TROW + mb * 2) = v;
    }
  __syncthreads();
  const int iG = tid >> 2, sub = tid & 3, t0 = m0 >> 5;
  #pragma unroll
  for (int tl = 0; tl < 8; ++tl) {
    short8 v = *(const short8*)(smem + iG * TROW + (tl * 32 + sub * 8) * 2);
    *(short8*)(ubT + (size_t)(t0 + tl) * TN + (size_t)(i0 + iG) * NBATCH + sub * 8) = v;
  }
}

// ---------------- K3: y = x_hist @ C^T + u @ D^T -> f32 ----------------
__global__ __launch_bounds__(512, 4) void gemm_y_k(const unsigned short* __restrict__ xh,
                                                   const float* __restrict__ u,
                                                   const unsigned short* __restrict__ Cb,
                                                   const unsigned short* __restrict__ Db,
                                                   float* __restrict__ y) {
  __shared__ __align__(16) char smem[2 * GBUF];  // 48KB -> 2+ WGs/CU
  const int tid = threadIdx.x, l = tid & 63, w = tid >> 6;
  const int wr = w >> 1, wc = w & 1, lr = l & 15, g = l >> 4;
  int m0, i0;
  swzgrid(blockIdx.x, m0, i0);
  f32x4 acc[4][4];
  #pragma unroll
  for (int mi = 0; mi < 4; ++mi)
    #pragma unroll
    for (int ni = 0; ni < 4; ++ni) acc[mi][ni] = (f32x4){0.f, 0.f, 0.f, 0.f};
  float4 pf[4];
  // prologue: step-0 tiles (xh / Cb)
  stage_a_bf16(xh, m0, 0, smem, w, l);
  stage_b_bf16(Cb, i0, 0, smem, w, l);
  __syncthreads();
  // 32 K-steps of 32: kt<16 -> pass1 (xh/Cb), kt>=16 -> pass2 (u/Db)
  for (int kt = 0; kt < 32; ++kt) {
    char* bufC = smem + (kt & 1) * GBUF;
    char* bufN = smem + ((kt + 1) & 1) * GBUF;
    if (kt < 15) {
      stage_a_bf16(xh, m0, (kt + 1) * 32, bufN, w, l);
      stage_b_bf16(Cb, i0, (kt + 1) * 32, bufN, w, l);
    } else if (kt == 15) {
      stage_b_bf16(Db, i0, 0, bufN, w, l);       // A for kt16 via f32_write
    } else if (kt < 31) {
      stage_b_bf16(Db, i0, (kt + 1 - 16) * 32, bufN, w, l);
    }
    compute32(bufC, acc, wr, wc, lr, g);
    if (kt == 14) {
      f32_issue(u, m0, 0, tid, pf);              // pf <- k-step 16 data
    } else if (kt >= 15 && kt < 31) {
      f32_write(bufN, tid, pf);                  // data for k-step kt+1
      if (kt < 30) f32_issue(u, m0, (kt + 2 - 16) * 32, tid, pf);
    }
    __syncthreads();
  }
  // epilogue: direct f32 stores (64B coalesced runs per 16-lane group)
  #pragma unroll
  for (int mi = 0; mi < 4; ++mi)
    #pragma unroll
    for (int ni = 0; ni < 4; ++ni) {
      const int ig = i0 + wc * 64 + ni * 16 + lr;
      const size_t mb = (size_t)(m0 + wr * 64 + mi * 16 + g * 4);
      #pragma unroll
      for (int r = 0; r < 4; ++r)
        y[(mb + r) * FD + ig] = acc[mi][ni][r];
    }
}

// ---------------- K2: chunked scan, 8 waves / group, padded LDS ------------
__global__ __launch_bounds__(512) void serial_k(const unsigned short* __restrict__ Ab,
                                                const unsigned short* __restrict__ ubT,
                                                unsigned short* __restrict__ xhist) {
  __shared__ __align__(16) unsigned char AldsB[512 * AROW];  // 139264 B
  __shared__ __align__(16) unsigned char xbufB[16 * XROW];   // 16640 B
  const int tid = threadIdx.x;
  const int l = tid & 63, w = tid >> 6;   // 8 waves; wave w owns cols [w*64,+64)
  const int lr = l & 15, g = l >> 4;      // g in 0..3
  const int b = blockIdx.x;
  const int chunk = b >> 1, nh = b & 1, n0 = nh * 16;
  const int tstart = chunk * CHUNK;
  const int t0 = (chunk == 0) ? 0 : tstart - WARM;
  const int nsteps = tstart + CHUNK - t0;

  // ---- A K<384 into registers: areg[4 col-tiles][12 k-frags] ----
  short8 areg[4][12];
  #pragma unroll
  for (int ct = 0; ct < 4; ++ct) {
    const int i = w * 64 + ct * 16 + lr;
    #pragma unroll
    for (int kb = 0; kb < 12; ++kb)
      areg[ct][kb] = *(const short8*)(Ab + (size_t)i * FD + kb * 32 + g * 8);
  }
  // ---- stage A[:, 384:512) into padded Alds (prologue only) ----
  for (int rr = 0; rr < 16; ++rr) {
    const int row = rr * 32 + (tid >> 4);   // 0..511
    const int kc = tid & 15;
    short8 v = *(const short8*)(Ab + (size_t)row * FD + KREG + kc * 8);
    *(short8*)(AldsB + row * AROW + kc * 16) = v;
  }
  BAR();

  // ---- incrementing bases with immediate offsets ----
  const unsigned short* ubp =
      ubT + (size_t)t0 * TN + (size_t)(w * 64 + lr) * NBATCH + n0 + g * 4;
  unsigned short* xhp =
      xhist + ((size_t)t0 * NBATCH + n0 + g * 4) * FD + w * 64 + lr;
  const unsigned char* xread = xbufB + lr * XROW + g * 16;             // +kb*64
  unsigned char* xwrite = xbufB + (g * 4) * XROW + (w * 64 + lr) * 2;  // +r*XROW+ct*32
  const unsigned char* aldsr[4];
  #pragma unroll
  for (int ct = 0; ct < 4; ++ct)
    aldsr[ct] = AldsB + (w * 64 + ct * 16 + lr) * AROW + g * 16;       // +kb2*64

  // ---- prologue ub prefetch ----
  short4v ubr[4];
  #pragma unroll
  for (int ct = 0; ct < 4; ++ct) ubr[ct] = *(const short4v*)(ubp + ct * 512);
  ubp += TN;

  for (int s = 0; s < nsteps; ++s) {
    const int t = t0 + s;
    f32x4 acc[4];
    #pragma unroll
    for (int ct = 0; ct < 4; ++ct)
      #pragma unroll
      for (int r = 0; r < 4; ++r) acc[ct][r] = bf2f((unsigned short)ubr[ct][r]);
    if (s + 1 < nsteps) {
      #pragma unroll
      for (int ct = 0; ct < 4; ++ct) ubr[ct] = *(const short4v*)(ubp + ct * 512);
    }
    ubp += TN;
    if (s > 0) {
      #pragma unroll
      for (int kb = 0; kb < 12; ++kb) {
        short8 xf = *(const short8*)(xread + kb * 64);
        #pragma unroll
        for (int ct = 0; ct < 4; ++ct) acc[ct] = mfma16(xf, areg[ct][kb], acc[ct]);
      }
      #pragma unroll
      for (int kb2 = 0; kb2 < 4; ++kb2) {
        short8 xf = *(const short8*)(xread + (12 + kb2) * 64);
        #pragma unroll
        for (int ct = 0; ct < 4; ++ct) {
          short8 af = *(const short8*)(aldsr[ct] + kb2 * 64);
          acc[ct] = mfma16(xf, af, acc[ct]);
        }
      }
    }
    // tanh -> bf16
    unsigned short hv[4][4];
    #pragma unroll
    for (int ct = 0; ct < 4; ++ct)
      #pragma unroll
      for (int r = 0; r < 4; ++r) {
        float e = __expf(2.f * acc[ct][r]);
        hv[ct][r] = f2bf_fast(1.f - 2.f * __builtin_amdgcn_rcpf(e + 1.f));
      }
    // xhist stores: fire-and-forget (no vmcnt drain at barriers)
    if (t >= tstart) {
      #pragma unroll
      for (int ct = 0; ct < 4; ++ct)
        #pragma unroll
        for (int r = 0; r < 4; ++r) xhp[r * FD + ct * 16] = hv[ct][r];
    }
    xhp += (size_t)NBATCH * FD;
    BAR();  // all xbuf reads of this step done (lgkm only)
    #pragma unroll
    for (int ct = 0; ct < 4; ++ct)
      #pragma unroll
      for (int r = 0; r < 4; ++r)
        *(unsigned short*)(xwrite + r * XROW + ct * 32) = hv[ct][r];
    BAR();  // xbuf writes visible before next step's reads
  }
}

// ---------------- launch ----------------
extern "C" void kernel_launch(void* const* d_in, const int* in_sizes, int n_in,
                              void* d_out, int out_size, void* d_ws, size_t ws_size,
                              hipStream_t stream) {
  const float* u = (const float*)d_in[0];
  const float* A = (const float*)d_in[1];
  const float* B = (const float*)d_in[2];
  const float* C = (const float*)d_in[3];
  const float* D = (const float*)d_in[4];
  float* y = (float*)d_out;

  char* ws = (char*)d_ws;
  size_t off = 0;
  unsigned short* ubT = (unsigned short*)(ws + off);   off += (size_t)M_TOT * FD * 2;
  unsigned short* xhist = (unsigned short*)(ws + off); off += (size_t)M_TOT * FD * 2;
  unsigned short* Ab = (unsigned short*)(ws + off);    off += (size_t)FD * FD * 2;
  unsigned short* Bb = (unsigned short*)(ws + off);    off += (size_t)FD * FD * 2;
  unsigned short* Cb = (unsigned short*)(ws + off);    off += (size_t)FD * FD * 2;
  unsigned short* Db = (unsigned short*)(ws + off);    off += (size_t)FD * FD * 2;

  cvt_k<<<dim3(FD * FD / (256 * 4), 4), 256, 0, stream>>>(A, B, C, D, Ab, Bb, Cb, Db);
  gemm_ub_k<<<dim3(NWGG, 1), 512, 0, stream>>>(u, Bb, ubT);
  serial_k<<<dim3(NGRP, 1), 512, 0, stream>>>(Ab, ubT, xhist);
  gemm_y_k<<<dim3(NWGG, 1), 512, 0, stream>>>(xhist, u, Cb, Db, y);
}